// Round 5
// baseline (299.399 us; speedup 1.0000x reference)
//
#include <hip/hip_runtime.h>
#include <stdint.h>

typedef unsigned int u32;
typedef unsigned long long u64;

#define NTOT 21824   // 128*128 + 64*64 + 32*32 + 16*16 + 8*8 = 341*64
#define NBATCH 16
#define TOPN 1000
#define MAXOBJ 100
#define LCAP 8192      // LDS candidate buffer capacity per batch
#define BINBASE 15616  // = 122 << 7 : first populated fine bin (score > 0.05 => exp >= 122)
#define NBINS 1024     // 768 real bins (exp 122..127 x 7 mantissa bits), padded

// -------------------------------------------------------------------------
// Stage 1: decode (argmax over 80 classes + score key).  Pure streaming,
// no LDS, no atomics.  Quad-per-location; each quad handles FOUR locations
// (loc0 + {0,64,128,192}) -> 20 dwordx4 + 4 ctr loads in flight per lane.
// decode was latency-bound (r3: 12.5% HBM, 7% VALU at 1-deep; 2-deep took
// it under the 48 us cutoff in r4) -> deepen MLP again.  NTOT = 341*64 so
// each 64-chunk's validity is block-uniform (no divergence).
// -------------------------------------------------------------------------
__device__ __forceinline__ void locate(
    int b, int loc,
    const float* __restrict__ cls0, const float* __restrict__ cls1,
    const float* __restrict__ cls2, const float* __restrict__ cls3,
    const float* __restrict__ cls4,
    const float* __restrict__ ctr0, const float* __restrict__ ctr1,
    const float* __restrict__ ctr2, const float* __restrict__ ctr3,
    const float* __restrict__ ctr4,
    const float*& cp, const float*& tp)
{
    if (loc < 16384)      { size_t o = (size_t)b*16384 + loc;          cp = cls0 + o*80; tp = ctr0 + o; }
    else if (loc < 20480) { size_t o = (size_t)b*4096  + (loc-16384);  cp = cls1 + o*80; tp = ctr1 + o; }
    else if (loc < 21504) { size_t o = (size_t)b*1024  + (loc-20480);  cp = cls2 + o*80; tp = ctr2 + o; }
    else if (loc < 21760) { size_t o = (size_t)b*256   + (loc-21504);  cp = cls3 + o*80; tp = ctr3 + o; }
    else                  { size_t o = (size_t)b*64    + (loc-21760);  cp = cls4 + o*80; tp = ctr4 + o; }
}

__global__ __launch_bounds__(256) void decode_kernel(
    const float* __restrict__ cls0, const float* __restrict__ cls1,
    const float* __restrict__ cls2, const float* __restrict__ cls3,
    const float* __restrict__ cls4,
    const float* __restrict__ ctr0, const float* __restrict__ ctr1,
    const float* __restrict__ ctr2, const float* __restrict__ ctr3,
    const float* __restrict__ ctr4,
    u32* __restrict__ keys, int* __restrict__ clsidx)
{
    int tid = threadIdx.x;
    int g = tid >> 2, j = tid & 3;          // quad index, quad sub-lane
    int b = blockIdx.y;
    int base = blockIdx.x * 256;

    const float* cp[4]; const float* tp[4]; bool v[4];
#pragma unroll
    for (int c = 0; c < 4; ++c) {
        v[c] = (base + 64 * c) < NTOT;       // block-uniform per chunk
        int loc = v[c] ? (base + 64 * c + g) : (base + g);
        locate(b, loc, cls0, cls1, cls2, cls3, cls4,
               ctr0, ctr1, ctr2, ctr3, ctr4, cp[c], tp[c]);
    }

    float4 a[4][5];
#pragma unroll
    for (int c = 0; c < 4; ++c) {
        const float4* c4 = (const float4*)cp[c];
#pragma unroll
        for (int q = 0; q < 5; ++q) a[c][q] = c4[j + 4*q];
    }
    float tv[4];
#pragma unroll
    for (int c = 0; c < 4; ++c) tv[c] = *tp[c];

    float maxv[4]; int arg[4];
#pragma unroll
    for (int c = 0; c < 4; ++c) {
        maxv[c] = -1.0f; arg[c] = 0;
#pragma unroll
        for (int q = 0; q < 5; ++q) {
            float4 vv = a[c][q];
            int ch = 16*q + 4*j;
            if (vv.x > maxv[c]) { maxv[c] = vv.x; arg[c] = ch;     }
            if (vv.y > maxv[c]) { maxv[c] = vv.y; arg[c] = ch + 1; }
            if (vv.z > maxv[c]) { maxv[c] = vv.z; arg[c] = ch + 2; }
            if (vv.w > maxv[c]) { maxv[c] = vv.w; arg[c] = ch + 3; }
        }
    }
    // quad reduction, exact first-max tie-break (lowest channel wins)
#pragma unroll
    for (int d = 1; d <= 2; d <<= 1) {
#pragma unroll
        for (int c = 0; c < 4; ++c) {
            float ov = __shfl_xor(maxv[c], d);
            int   oa = __shfl_xor(arg[c], d);
            if (ov > maxv[c] || (ov == maxv[c] && oa < arg[c])) { maxv[c] = ov; arg[c] = oa; }
        }
    }
    if (j == 0) {
#pragma unroll
        for (int c = 0; c < 4; ++c) {
            if (v[c]) {
                float score = sqrtf(maxv[c] * tv[c]);   // correctly-rounded fp32 sqrt
                u32 key = (score > 0.05f) ? (__float_as_uint(score) | 0x80000000u) : 0u;
                size_t o = (size_t)b * NTOT + base + 64 * c + g;
                keys[o] = key;
                clsidx[o] = arg[c];
            }
        }
    }
}

// -------------------------------------------------------------------------
// Stage 2: fused topk = pivot + gather + rank.  1 block/batch, 1024 thr.
//  - pass A (keys, L2-hot): 1024-bin LDS histogram of fine bin
//    ((key>>16)&0x7FFF)-BINBASE; score in (0.05,1] => bin in [0,768).
//  - block suffix scan (1 bin/thread) locates exact pivot bin (r4-verified).
//  - pass B (keys): compact all keys >= P into LDS cand[] (wave-aggregated
//    LDS counter; r1/r2-verified ballot code).  M ~= target + ~170 << LCAP.
//  - rank-by-count on LDS cand (r0-verified readlane loop, source now LDS)
//    + box decode + scatter.  Defaults written up-front (barrier-ordered
//    before scatter).  No global candbuf/gcnt/params traffic at all.
// -------------------------------------------------------------------------
__global__ __launch_bounds__(1024) void topk_kernel(
    const u32* __restrict__ keys, const int* __restrict__ clsidx,
    const float* __restrict__ reg0, const float* __restrict__ reg1,
    const float* __restrict__ reg2, const float* __restrict__ reg3,
    const float* __restrict__ reg4,
    float* __restrict__ tscore, float* __restrict__ tcls, float4* __restrict__ tbox)
{
    __shared__ u64 cand[LCAP];           // 64 KB
    __shared__ u32 shist[NBINS];         //  4 KB
    __shared__ u32 s_wtot[16];
    __shared__ int s_tf;
    __shared__ u32 s_cnt;
    int b = blockIdx.x, tid = threadIdx.x;
    int lane = tid & 63, wave = tid >> 6;
    const u32* kb = keys + (size_t)b * NTOT;

    for (int i = tid; i < TOPN; i += 1024) {
        size_t o = (size_t)b * TOPN + i;
        tscore[o] = -1.0f; tcls[o] = -1.0f;
        tbox[o] = make_float4(0.f, 0.f, 0.f, 0.f);
    }
    shist[tid] = 0;
    if (tid == 0) { s_tf = -1; s_cnt = 0; }
    __syncthreads();

    // ---- pass A: histogram ----
    for (int i = tid; i < NTOT; i += 1024) {
        u32 k = kb[i];
        if (k) {
            int v = (int)((k >> 16) & 0x7FFFu) - BINBASE;
            v = v < 0 ? 0 : (v > NBINS - 1 ? NBINS - 1 : v);
            atomicAdd(&shist[v], 1u);
        }
    }
    __syncthreads();

    // ---- block-wide inclusive suffix scan, 1 bin per thread ----
    u32 h = shist[tid];
    u32 x = h;
#pragma unroll
    for (int off = 1; off < 64; off <<= 1) {
        u32 y = __shfl_down(x, off);
        if (lane + off < 64) x += y;
    }
    if (lane == 0) s_wtot[wave] = x;
    __syncthreads();
    u32 wsuf = 0, tot = 0;
    for (int w2 = 0; w2 < 16; ++w2) { u32 v = s_wtot[w2]; tot += v; if (w2 > wave) wsuf += v; }
    u32 suffix_incl = x + wsuf;          // #keys with bin >= tid
    u32 target = (tot < TOPN) ? tot : TOPN;

    if (target > 0 && suffix_incl >= target) atomicMax(&s_tf, tid);
    __syncthreads();
    u32 P;
    {
        int t0 = s_tf;                   // uniform: tot/target uniform, s_tf shared
        if (target == 0)        P = 0xFFFFFFFFu;   // nothing passes
        else if (tot <= TOPN)   P = 1u;            // take every valid key
        else                    P = ((u32)(t0 + BINBASE) << 16) | 0x80000000u;
    }

    // ---- pass B: compact keys >= P into LDS cand ----
    for (int base = 0; base < NTOT; base += 1024) {
        int i = base + tid;
        u32 k = (i < NTOT) ? kb[i] : 0u;
        bool pass = (k != 0u) && (k >= P);
        u64 mask = __ballot(pass);
        u32 wbase = 0;
        if (lane == 0 && mask) wbase = atomicAdd(&s_cnt, (u32)__popcll(mask));
        wbase = __shfl(wbase, 0);
        if (pass) {
            u32 pos = wbase + (u32)__popcll(mask & ((1ull << lane) - 1ull));
            if (pos < LCAP) cand[pos] = ((u64)k << 32) | (u32)(~i);
        }
    }
    __syncthreads();
    u32 M = s_cnt; if (M > LCAP) M = LCAP;
    u32 Mr = (M + 63u) & ~63u;

    // ---- rank-by-count + scatter (readlane loop over LDS cand) ----
    for (u32 base = wave * 64; base < M; base += 16 * 64) {
        u32 i0 = base + lane;
        bool val = (i0 < M);
        u64 e = val ? cand[i0] : ~0ull;
        u32 r = 0;
        for (u32 c0 = 0; c0 < Mr; c0 += 64) {
            u32 jj = c0 + lane;
            u64 vv = (jj < M) ? cand[jj] : 0ull;   // 0 is never > any candidate
            u32 vlo = (u32)vv, vhi = (u32)(vv >> 32);
#pragma unroll
            for (int s = 0; s < 64; ++s) {
                u32 lo = (u32)__builtin_amdgcn_readlane((int)vlo, s);
                u32 hi = (u32)__builtin_amdgcn_readlane((int)vhi, s);
                u64 vj = ((u64)hi << 32) | lo;
                r += (vj > e) ? 1u : 0u;
            }
        }
        if (val && r < target) {
            u32 k = (u32)(e >> 32);
            u32 loc = ~(u32)e;
            const float* rp; float st; u32 li; int wsh;
            if (loc < 16384u)      { li = loc;          wsh = 7; st = 8.f;   rp = reg0 + ((size_t)b*16384 + li)*4; }
            else if (loc < 20480u) { li = loc - 16384u; wsh = 6; st = 16.f;  rp = reg1 + ((size_t)b*4096  + li)*4; }
            else if (loc < 21504u) { li = loc - 20480u; wsh = 5; st = 32.f;  rp = reg2 + ((size_t)b*1024  + li)*4; }
            else if (loc < 21760u) { li = loc - 21504u; wsh = 4; st = 64.f;  rp = reg3 + ((size_t)b*256   + li)*4; }
            else                   { li = loc - 21760u; wsh = 3; st = 128.f; rp = reg4 + ((size_t)b*64    + li)*4; }
            u32 wx = li & ((1u << wsh) - 1u);
            u32 hy = li >> wsh;
            float px = ((float)wx + 0.5f) * st;
            float py = ((float)hy + 0.5f) * st;
            float4 rg = *(const float4*)rp;
            float4 bx;
            bx.x = truncf(px - rg.x); bx.y = truncf(py - rg.y);
            bx.z = truncf(px + rg.z); bx.w = truncf(py + rg.w);
            size_t src = (size_t)b * NTOT + loc;
            size_t o = (size_t)b * TOPN + r;
            tscore[o] = __uint_as_float(k & 0x7FFFFFFFu);
            tcls[o] = (float)clsidx[src];
            tbox[o] = bx;
        }
    }
}

// -------------------------------------------------------------------------
// Stage 3: suppression-bit matrix.  4 rows per 256-thread block.
// -------------------------------------------------------------------------
__global__ __launch_bounds__(256) void iou_kernel(
    const float4* __restrict__ tbox, u64* __restrict__ sup)
{
    __shared__ float4 sbox[TOPN];
    int b = blockIdx.y;
    int tid = threadIdx.x, lane = tid & 63, wave = tid >> 6;
    const float4* tb = tbox + (size_t)b * TOPN;
    for (int i = tid; i < TOPN; i += 256) sbox[i] = tb[i];
    __syncthreads();
    int i = blockIdx.x * 4 + wave;
    float4 bi = sbox[i];
    float areai = fmaxf((bi.z - bi.x) * (bi.w - bi.y), 0.0001f);
    u64* row = sup + ((size_t)b * TOPN + i) * 16;
#pragma unroll
    for (int w = 0; w < 16; ++w) {
        int col = w * 64 + lane;
        bool bit = false;
        if (col < TOPN) {
            float4 bj = sbox[col];
            float areaj = fmaxf((bj.z - bj.x) * (bj.w - bj.y), 0.0001f);
            float tlx = fmaxf(bi.x, bj.x), tly = fmaxf(bi.y, bj.y);
            float brx = fminf(bi.z, bj.z), bry = fminf(bi.w, bj.w);
            float ow = fmaxf(brx - tlx, 0.f), oh = fmaxf(bry - tly, 0.f);
            float inter = ow * oh;
            float uni = fmaxf(areai + areaj - inter, 0.0001f);
            bit = (col > i) && (inter / uni >= 0.6f);
        }
        u64 m = __ballot(bit);
        if (lane == 0) row[w] = m;
    }
}

// -------------------------------------------------------------------------
// Stage 4: greedy serial scan + popcount-rank output.
// -------------------------------------------------------------------------
#define CHROWS 128
#define NCHUNK 8

__global__ __launch_bounds__(1024) void finalize_kernel(
    const float* __restrict__ tscore, const float* __restrict__ tcls,
    const float4* __restrict__ tbox, const u64* __restrict__ sup,
    float* __restrict__ out)
{
    __shared__ u64 mat[2][CHROWS * 16];
    __shared__ u32 validsh[TOPN];
    __shared__ u64 removed_sh[16];
    __shared__ u32 wpref[17];
    int b = blockIdx.x, tid = threadIdx.x;
    int wave = tid >> 6, lane = tid & 63;

    for (int i = tid; i < TOPN; i += 1024)
        validsh[i] = (tscore[(size_t)b * TOPN + i] > 0.05f) ? 1u : 0u;

    const u64* supb = sup + (size_t)b * TOPN * 16;
    for (int idx = tid; idx < CHROWS * 16; idx += 1024)
        mat[0][idx] = supb[idx];
    __syncthreads();

    u64 my = 0;
    if (wave == 0) {
#pragma unroll
        for (int w2 = 0; w2 < 16; ++w2) {
            int i = w2 * 64 + lane;
            bool v = (i < TOPN) ? (validsh[i] != 0) : false;
            u64 m = __ballot(v);
            if (lane == w2) my = ~m;
        }
    }

    for (int chunk = 0; chunk < NCHUNK; ++chunk) {
        if (wave > 0 && chunk + 1 < NCHUNK) {
            int nr = (chunk + 1 == NCHUNK - 1) ? (TOPN - (NCHUNK - 1) * CHROWS) : CHROWS;
            const u64* src = supb + (size_t)(chunk + 1) * CHROWS * 16;
            u64* dst = mat[(chunk + 1) & 1];
            for (int idx = tid - 64; idx < nr * 16; idx += 960)
                dst[idx] = src[idx];
        }
        if (wave == 0) {
            int r0 = chunk * CHROWS;
            int rows = (chunk == NCHUNK - 1) ? (TOPN - r0) : CHROWS;
            int lw = lane & 15;
            const u64* M = mat[chunk & 1];
            for (int sub = 0; sub < rows; sub += 64) {
                int w2 = (r0 + sub) >> 6;
                u64 cur = __shfl(my, w2);
                int nsub = rows - sub; if (nsub > 64) nsub = 64;
                const u64* R = M + sub * 16;
                int ngrp = nsub >> 3;
                u64 cme[8], cww[8];
#pragma unroll
                for (int g = 0; g < 8; ++g) { cme[g] = R[g*16 + lw]; cww[g] = R[g*16 + w2]; }
                for (int grp = 0; grp < ngrp; ++grp) {
                    u64 nme[8] = {0,0,0,0,0,0,0,0}, nww[8] = {0,0,0,0,0,0,0,0};
                    if (grp + 1 < ngrp) {
                        const u64* Rn = R + (grp + 1) * 128;
#pragma unroll
                        for (int g = 0; g < 8; ++g) { nme[g] = Rn[g*16 + lw]; nww[g] = Rn[g*16 + w2]; }
                    }
#pragma unroll
                    for (int g = 0; g < 8; ++g) {
                        int u = grp * 8 + g;
                        u64 bit = (cur >> u) & 1ull;
                        u64 act = bit - 1ull;
                        cur |= cww[g] & act;
                        my  |= cme[g] & act;
                    }
#pragma unroll
                    for (int g = 0; g < 8; ++g) { cme[g] = nme[g]; cww[g] = nww[g]; }
                }
            }
        }
        __syncthreads();
    }
    if (wave == 0) {
        if (lane < 16) removed_sh[lane] = my;
        u32 pc = (lane < 16) ? (u32)__popcll(~my) : 0u;
#pragma unroll
        for (int off = 1; off < 16; off <<= 1) {
            u32 y = __shfl_up(pc, off);
            if (lane >= off) pc += y;
        }
        if (lane < 16) wpref[lane + 1] = pc;
        if (lane == 0) wpref[0] = 0;
    }
    __syncthreads();

    float* out_s = out;
    float* out_c = out + NBATCH * MAXOBJ;
    float* out_b = out + 2 * NBATCH * MAXOBJ;
    if (tid < MAXOBJ)     { out_s[b * MAXOBJ + tid] = -1.f; out_c[b * MAXOBJ + tid] = -1.f; }
    if (tid < MAXOBJ * 4) out_b[b * MAXOBJ * 4 + tid] = 0.f;
    __syncthreads();
    if (tid < TOPN) {
        u64 kw = ~removed_sh[tid >> 6];       // keep-word (invalid already removed)
        if ((kw >> (tid & 63)) & 1ull) {
            int rank = (int)wpref[tid >> 6] + (int)__popcll(kw & ((1ull << (tid & 63)) - 1ull));
            if (rank < MAXOBJ) {
                size_t o = (size_t)b * TOPN + tid;
                out_s[b * MAXOBJ + rank] = tscore[o];
                out_c[b * MAXOBJ + rank] = tcls[o];
                ((float4*)out_b)[b * MAXOBJ + rank] = tbox[o];
            }
        }
    }
}

// -------------------------------------------------------------------------
// Workspace layout (bytes), total 5,225,472.  Nothing needs pre-zeroing:
//   keys    u32 [16][21824]     @ 0
//   clsidx  i32 [16][21824]     @ 1,396,736
//   tscore  f32 [16][1000]      @ 2,793,472
//   tcls    f32 [16][1000]      @ 2,857,472
//   tbox    f4  [16][1000]      @ 2,921,472
//   sup     u64 [16][1000][16]  @ 3,177,472
// -------------------------------------------------------------------------
extern "C" void kernel_launch(void* const* d_in, const int* in_sizes, int n_in,
                              void* d_out, int out_size, void* d_ws, size_t ws_size,
                              hipStream_t stream) {
    (void)in_sizes; (void)n_in; (void)out_size; (void)ws_size;
    const float* cls[5]; const float* reg[5]; const float* ctr[5];
    for (int l = 0; l < 5; ++l) {
        cls[l] = (const float*)d_in[4 * l + 0];
        reg[l] = (const float*)d_in[4 * l + 1];
        ctr[l] = (const float*)d_in[4 * l + 2];
    }
    char* w = (char*)d_ws;
    u32*    keys   = (u32*)(w + 0);
    int*    clsidx = (int*)(w + 1396736);
    float*  tscore = (float*)(w + 2793472);
    float*  tcls   = (float*)(w + 2857472);
    float4* tbox   = (float4*)(w + 2921472);
    u64*    sup    = (u64*)(w + 3177472);

    decode_kernel<<<dim3((NTOT + 255) / 256, NBATCH), 256, 0, stream>>>(
        cls[0], cls[1], cls[2], cls[3], cls[4],
        ctr[0], ctr[1], ctr[2], ctr[3], ctr[4],
        keys, clsidx);
    topk_kernel<<<NBATCH, 1024, 0, stream>>>(keys, clsidx,
                                             reg[0], reg[1], reg[2], reg[3], reg[4],
                                             tscore, tcls, tbox);
    iou_kernel<<<dim3(TOPN / 4, NBATCH), 256, 0, stream>>>(tbox, sup);
    finalize_kernel<<<NBATCH, 1024, 0, stream>>>(tscore, tcls, tbox, sup, (float*)d_out);
}

// Round 6
// 276.108 us; speedup vs baseline: 1.0844x; 1.0844x over previous
//
#include <hip/hip_runtime.h>
#include <stdint.h>

typedef unsigned int u32;
typedef unsigned long long u64;

#define NTOT 21824   // 128*128 + 64*64 + 32*32 + 16*16 + 8*8 = 341*64
#define NBATCH 16
#define TOPN 1000
#define MAXOBJ 100
#define CAPC 8192      // global candidate buffer capacity per batch
#define BINBASE 15616  // = 122 << 7 : first populated fine bin (score > 0.05 => exp >= 122)
#define NBINS 1024     // 768 real bins (exp 122..127 x 7 mantissa bits), padded

// -------------------------------------------------------------------------
// Stage 1: decode (argmax over 80 classes + score key).  Pure streaming,
// no LDS, no atomics.  Quad-per-location; each quad handles FOUR locations
// (loc0 + {0,64,128,192}) -> 20 dwordx4 + 4 ctr loads in flight per lane
// (r3 showed decode latency-bound at 1-deep: 12.5% HBM, 7% VALU; 2-deep
// verified faster in r4; 4-deep r5-verified correct).  NTOT = 341*64 so
// each 64-chunk's validity is block-uniform (no divergence).
// -------------------------------------------------------------------------
__device__ __forceinline__ void locate(
    int b, int loc,
    const float* __restrict__ cls0, const float* __restrict__ cls1,
    const float* __restrict__ cls2, const float* __restrict__ cls3,
    const float* __restrict__ cls4,
    const float* __restrict__ ctr0, const float* __restrict__ ctr1,
    const float* __restrict__ ctr2, const float* __restrict__ ctr3,
    const float* __restrict__ ctr4,
    const float*& cp, const float*& tp)
{
    if (loc < 16384)      { size_t o = (size_t)b*16384 + loc;          cp = cls0 + o*80; tp = ctr0 + o; }
    else if (loc < 20480) { size_t o = (size_t)b*4096  + (loc-16384);  cp = cls1 + o*80; tp = ctr1 + o; }
    else if (loc < 21504) { size_t o = (size_t)b*1024  + (loc-20480);  cp = cls2 + o*80; tp = ctr2 + o; }
    else if (loc < 21760) { size_t o = (size_t)b*256   + (loc-21504);  cp = cls3 + o*80; tp = ctr3 + o; }
    else                  { size_t o = (size_t)b*64    + (loc-21760);  cp = cls4 + o*80; tp = ctr4 + o; }
}

__global__ __launch_bounds__(256) void decode_kernel(
    const float* __restrict__ cls0, const float* __restrict__ cls1,
    const float* __restrict__ cls2, const float* __restrict__ cls3,
    const float* __restrict__ cls4,
    const float* __restrict__ ctr0, const float* __restrict__ ctr1,
    const float* __restrict__ ctr2, const float* __restrict__ ctr3,
    const float* __restrict__ ctr4,
    u32* __restrict__ keys, int* __restrict__ clsidx)
{
    int tid = threadIdx.x;
    int g = tid >> 2, j = tid & 3;          // quad index, quad sub-lane
    int b = blockIdx.y;
    int base = blockIdx.x * 256;

    const float* cp[4]; const float* tp[4]; bool v[4];
#pragma unroll
    for (int c = 0; c < 4; ++c) {
        v[c] = (base + 64 * c) < NTOT;       // block-uniform per chunk
        int loc = v[c] ? (base + 64 * c + g) : (base + g);
        locate(b, loc, cls0, cls1, cls2, cls3, cls4,
               ctr0, ctr1, ctr2, ctr3, ctr4, cp[c], tp[c]);
    }

    float4 a[4][5];
#pragma unroll
    for (int c = 0; c < 4; ++c) {
        const float4* c4 = (const float4*)cp[c];
#pragma unroll
        for (int q = 0; q < 5; ++q) a[c][q] = c4[j + 4*q];
    }
    float tv[4];
#pragma unroll
    for (int c = 0; c < 4; ++c) tv[c] = *tp[c];

    float maxv[4]; int arg[4];
#pragma unroll
    for (int c = 0; c < 4; ++c) {
        maxv[c] = -1.0f; arg[c] = 0;
#pragma unroll
        for (int q = 0; q < 5; ++q) {
            float4 vv = a[c][q];
            int ch = 16*q + 4*j;
            if (vv.x > maxv[c]) { maxv[c] = vv.x; arg[c] = ch;     }
            if (vv.y > maxv[c]) { maxv[c] = vv.y; arg[c] = ch + 1; }
            if (vv.z > maxv[c]) { maxv[c] = vv.z; arg[c] = ch + 2; }
            if (vv.w > maxv[c]) { maxv[c] = vv.w; arg[c] = ch + 3; }
        }
    }
    // quad reduction, exact first-max tie-break (lowest channel wins)
#pragma unroll
    for (int d = 1; d <= 2; d <<= 1) {
#pragma unroll
        for (int c = 0; c < 4; ++c) {
            float ov = __shfl_xor(maxv[c], d);
            int   oa = __shfl_xor(arg[c], d);
            if (ov > maxv[c] || (ov == maxv[c] && oa < arg[c])) { maxv[c] = ov; arg[c] = oa; }
        }
    }
    if (j == 0) {
#pragma unroll
        for (int c = 0; c < 4; ++c) {
            if (v[c]) {
                float score = sqrtf(maxv[c] * tv[c]);   // correctly-rounded fp32 sqrt
                u32 key = (score > 0.05f) ? (__float_as_uint(score) | 0x80000000u) : 0u;
                size_t o = (size_t)b * NTOT + base + 64 * c + g;
                keys[o] = key;
                clsidx[o] = arg[c];
            }
        }
    }
}

// -------------------------------------------------------------------------
// Stage 2: fused pivot + gather.  1 block/batch, 1024 thr.  O(N) passes
// ONLY (r5 lesson: the O(M^2) rank must stay out of 16-block kernels).
//  - pass A (keys, L2-hot): 1024-bin LDS histogram of fine bin
//    ((key>>16)&0x7FFF)-BINBASE; score in (0.05,1] => bin in [0,768).
//  - block suffix scan (1 bin/thread) locates exact pivot bin (r4-verified).
//  - pass B: compact all keys >= P into GLOBAL candbuf (LDS counter,
//    r5-verified ballot code).  M ~= target + ~170 << CAPC.
//  - writes output defaults.  params[2b] = {M, target}.
// -------------------------------------------------------------------------
__global__ __launch_bounds__(1024) void pivot_gather_kernel(
    const u32* __restrict__ keys, u64* __restrict__ candbuf, u32* __restrict__ params,
    float* __restrict__ tscore, float* __restrict__ tcls, float4* __restrict__ tbox)
{
    __shared__ u32 shist[NBINS];
    __shared__ u32 s_wtot[16];
    __shared__ int s_tf;
    __shared__ u32 s_cnt;
    int b = blockIdx.x, tid = threadIdx.x;
    int lane = tid & 63, wave = tid >> 6;
    const u32* kb = keys + (size_t)b * NTOT;

    for (int i = tid; i < TOPN; i += 1024) {
        size_t o = (size_t)b * TOPN + i;
        tscore[o] = -1.0f; tcls[o] = -1.0f;
        tbox[o] = make_float4(0.f, 0.f, 0.f, 0.f);
    }
    shist[tid] = 0;
    if (tid == 0) { s_tf = -1; s_cnt = 0; }
    __syncthreads();

    // ---- pass A: histogram ----
    for (int i = tid; i < NTOT; i += 1024) {
        u32 k = kb[i];
        if (k) {
            int v = (int)((k >> 16) & 0x7FFFu) - BINBASE;
            v = v < 0 ? 0 : (v > NBINS - 1 ? NBINS - 1 : v);
            atomicAdd(&shist[v], 1u);
        }
    }
    __syncthreads();

    // ---- block-wide inclusive suffix scan, 1 bin per thread ----
    u32 h = shist[tid];
    u32 x = h;
#pragma unroll
    for (int off = 1; off < 64; off <<= 1) {
        u32 y = __shfl_down(x, off);
        if (lane + off < 64) x += y;
    }
    if (lane == 0) s_wtot[wave] = x;
    __syncthreads();
    u32 wsuf = 0, tot = 0;
    for (int w2 = 0; w2 < 16; ++w2) { u32 v = s_wtot[w2]; tot += v; if (w2 > wave) wsuf += v; }
    u32 suffix_incl = x + wsuf;          // #keys with bin >= tid
    u32 target = (tot < TOPN) ? tot : TOPN;

    if (target > 0 && suffix_incl >= target) atomicMax(&s_tf, tid);
    __syncthreads();
    u32 P;
    {
        int t0 = s_tf;                   // uniform: tot/target uniform, s_tf shared
        if (target == 0)        P = 0xFFFFFFFFu;   // nothing passes
        else if (tot <= TOPN)   P = 1u;            // take every valid key
        else                    P = ((u32)(t0 + BINBASE) << 16) | 0x80000000u;
    }

    // ---- pass B: compact keys >= P into global candbuf ----
    for (int base = 0; base < NTOT; base += 1024) {
        int i = base + tid;
        u32 k = (i < NTOT) ? kb[i] : 0u;
        bool pass = (k != 0u) && (k >= P);
        u64 mask = __ballot(pass);
        u32 wbase = 0;
        if (lane == 0 && mask) wbase = atomicAdd(&s_cnt, (u32)__popcll(mask));
        wbase = __shfl(wbase, 0);
        if (pass) {
            u32 pos = wbase + (u32)__popcll(mask & ((1ull << lane) - 1ull));
            if (pos < CAPC) candbuf[(size_t)b * CAPC + pos] = ((u64)k << 32) | (u32)(~i);
        }
    }
    __syncthreads();
    if (tid == 0) {
        u32 M = s_cnt; if (M > CAPC) M = CAPC;
        params[2 * b] = M;
        params[2 * b + 1] = target;
    }
}

// -------------------------------------------------------------------------
// Stage 3: rank-by-count + scatter, DISTRIBUTED (8 blocks x 16 batches so
// the O(M^2) count runs on 128 blocks, ~1 wave-iteration each).  Box
// decode (reg read + trunc) for the <= CAPC candidates only (exact same
// fp32 ops as the reference; px,py recomputed exactly).
// -------------------------------------------------------------------------
__global__ __launch_bounds__(256) void rank_kernel(
    const u64* __restrict__ candbuf, const u32* __restrict__ params,
    const int* __restrict__ clsidx,
    const float* __restrict__ reg0, const float* __restrict__ reg1,
    const float* __restrict__ reg2, const float* __restrict__ reg3,
    const float* __restrict__ reg4,
    float* __restrict__ tscore, float* __restrict__ tcls, float4* __restrict__ tbox)
{
    int b = blockIdx.y;
    int lane = threadIdx.x & 63;
    u32 M = params[2 * b];
    u32 target = params[2 * b + 1];
    const u64* cb = candbuf + (size_t)b * CAPC;
    u32 Mr = (M + 63u) & ~63u;

    u32 wbase0 = blockIdx.x * 256 + (threadIdx.x & ~63u);
    for (u32 base = wbase0; base < M; base += 8 * 256) {   // uniform per wave
        u32 i0 = base + lane;
        bool val = (i0 < M);
        u64 e = val ? cb[i0] : ~0ull;
        u32 r = 0;
        for (u32 c0 = 0; c0 < Mr; c0 += 64) {
            u32 j = c0 + lane;
            u64 v = (j < M) ? cb[j] : 0ull;   // 0 is never > any candidate
            u32 vlo = (u32)v, vhi = (u32)(v >> 32);
#pragma unroll
            for (int s = 0; s < 64; ++s) {
                u32 lo = (u32)__builtin_amdgcn_readlane((int)vlo, s);
                u32 hi = (u32)__builtin_amdgcn_readlane((int)vhi, s);
                u64 vj = ((u64)hi << 32) | lo;
                r += (vj > e) ? 1u : 0u;
            }
        }
        if (val && r < target) {
            u32 k = (u32)(e >> 32);
            u32 loc = ~(u32)e;
            const float* rp; float st; u32 li; int wsh;
            if (loc < 16384u)      { li = loc;          wsh = 7; st = 8.f;   rp = reg0 + ((size_t)b*16384 + li)*4; }
            else if (loc < 20480u) { li = loc - 16384u; wsh = 6; st = 16.f;  rp = reg1 + ((size_t)b*4096  + li)*4; }
            else if (loc < 21504u) { li = loc - 20480u; wsh = 5; st = 32.f;  rp = reg2 + ((size_t)b*1024  + li)*4; }
            else if (loc < 21760u) { li = loc - 21504u; wsh = 4; st = 64.f;  rp = reg3 + ((size_t)b*256   + li)*4; }
            else                   { li = loc - 21760u; wsh = 3; st = 128.f; rp = reg4 + ((size_t)b*64    + li)*4; }
            u32 wx = li & ((1u << wsh) - 1u);
            u32 hy = li >> wsh;
            float px = ((float)wx + 0.5f) * st;
            float py = ((float)hy + 0.5f) * st;
            float4 rg = *(const float4*)rp;
            float4 bx;
            bx.x = truncf(px - rg.x); bx.y = truncf(py - rg.y);
            bx.z = truncf(px + rg.z); bx.w = truncf(py + rg.w);
            size_t src = (size_t)b * NTOT + loc;
            size_t o = (size_t)b * TOPN + r;
            tscore[o] = __uint_as_float(k & 0x7FFFFFFFu);
            tcls[o] = (float)clsidx[src];
            tbox[o] = bx;
        }
    }
}

// -------------------------------------------------------------------------
// Stage 4: suppression-bit matrix.  4 rows per 256-thread block.
// -------------------------------------------------------------------------
__global__ __launch_bounds__(256) void iou_kernel(
    const float4* __restrict__ tbox, u64* __restrict__ sup)
{
    __shared__ float4 sbox[TOPN];
    int b = blockIdx.y;
    int tid = threadIdx.x, lane = tid & 63, wave = tid >> 6;
    const float4* tb = tbox + (size_t)b * TOPN;
    for (int i = tid; i < TOPN; i += 256) sbox[i] = tb[i];
    __syncthreads();
    int i = blockIdx.x * 4 + wave;
    float4 bi = sbox[i];
    float areai = fmaxf((bi.z - bi.x) * (bi.w - bi.y), 0.0001f);
    u64* row = sup + ((size_t)b * TOPN + i) * 16;
#pragma unroll
    for (int w = 0; w < 16; ++w) {
        int col = w * 64 + lane;
        bool bit = false;
        if (col < TOPN) {
            float4 bj = sbox[col];
            float areaj = fmaxf((bj.z - bj.x) * (bj.w - bj.y), 0.0001f);
            float tlx = fmaxf(bi.x, bj.x), tly = fmaxf(bi.y, bj.y);
            float brx = fminf(bi.z, bj.z), bry = fminf(bi.w, bj.w);
            float ow = fmaxf(brx - tlx, 0.f), oh = fmaxf(bry - tly, 0.f);
            float inter = ow * oh;
            float uni = fmaxf(areai + areaj - inter, 0.0001f);
            bit = (col > i) && (inter / uni >= 0.6f);
        }
        u64 m = __ballot(bit);
        if (lane == 0) row[w] = m;
    }
}

// -------------------------------------------------------------------------
// Stage 5: greedy serial scan + popcount-rank output.
// -------------------------------------------------------------------------
#define CHROWS 128
#define NCHUNK 8

__global__ __launch_bounds__(1024) void finalize_kernel(
    const float* __restrict__ tscore, const float* __restrict__ tcls,
    const float4* __restrict__ tbox, const u64* __restrict__ sup,
    float* __restrict__ out)
{
    __shared__ u64 mat[2][CHROWS * 16];
    __shared__ u32 validsh[TOPN];
    __shared__ u64 removed_sh[16];
    __shared__ u32 wpref[17];
    int b = blockIdx.x, tid = threadIdx.x;
    int wave = tid >> 6, lane = tid & 63;

    for (int i = tid; i < TOPN; i += 1024)
        validsh[i] = (tscore[(size_t)b * TOPN + i] > 0.05f) ? 1u : 0u;

    const u64* supb = sup + (size_t)b * TOPN * 16;
    for (int idx = tid; idx < CHROWS * 16; idx += 1024)
        mat[0][idx] = supb[idx];
    __syncthreads();

    u64 my = 0;
    if (wave == 0) {
#pragma unroll
        for (int w2 = 0; w2 < 16; ++w2) {
            int i = w2 * 64 + lane;
            bool v = (i < TOPN) ? (validsh[i] != 0) : false;
            u64 m = __ballot(v);
            if (lane == w2) my = ~m;
        }
    }

    for (int chunk = 0; chunk < NCHUNK; ++chunk) {
        if (wave > 0 && chunk + 1 < NCHUNK) {
            int nr = (chunk + 1 == NCHUNK - 1) ? (TOPN - (NCHUNK - 1) * CHROWS) : CHROWS;
            const u64* src = supb + (size_t)(chunk + 1) * CHROWS * 16;
            u64* dst = mat[(chunk + 1) & 1];
            for (int idx = tid - 64; idx < nr * 16; idx += 960)
                dst[idx] = src[idx];
        }
        if (wave == 0) {
            int r0 = chunk * CHROWS;
            int rows = (chunk == NCHUNK - 1) ? (TOPN - r0) : CHROWS;
            int lw = lane & 15;
            const u64* M = mat[chunk & 1];
            for (int sub = 0; sub < rows; sub += 64) {
                int w2 = (r0 + sub) >> 6;
                u64 cur = __shfl(my, w2);
                int nsub = rows - sub; if (nsub > 64) nsub = 64;
                const u64* R = M + sub * 16;
                int ngrp = nsub >> 3;
                u64 cme[8], cww[8];
#pragma unroll
                for (int g = 0; g < 8; ++g) { cme[g] = R[g*16 + lw]; cww[g] = R[g*16 + w2]; }
                for (int grp = 0; grp < ngrp; ++grp) {
                    u64 nme[8] = {0,0,0,0,0,0,0,0}, nww[8] = {0,0,0,0,0,0,0,0};
                    if (grp + 1 < ngrp) {
                        const u64* Rn = R + (grp + 1) * 128;
#pragma unroll
                        for (int g = 0; g < 8; ++g) { nme[g] = Rn[g*16 + lw]; nww[g] = Rn[g*16 + w2]; }
                    }
#pragma unroll
                    for (int g = 0; g < 8; ++g) {
                        int u = grp * 8 + g;
                        u64 bit = (cur >> u) & 1ull;
                        u64 act = bit - 1ull;
                        cur |= cww[g] & act;
                        my  |= cme[g] & act;
                    }
#pragma unroll
                    for (int g = 0; g < 8; ++g) { cme[g] = nme[g]; cww[g] = nww[g]; }
                }
            }
        }
        __syncthreads();
    }
    if (wave == 0) {
        if (lane < 16) removed_sh[lane] = my;
        u32 pc = (lane < 16) ? (u32)__popcll(~my) : 0u;
#pragma unroll
        for (int off = 1; off < 16; off <<= 1) {
            u32 y = __shfl_up(pc, off);
            if (lane >= off) pc += y;
        }
        if (lane < 16) wpref[lane + 1] = pc;
        if (lane == 0) wpref[0] = 0;
    }
    __syncthreads();

    float* out_s = out;
    float* out_c = out + NBATCH * MAXOBJ;
    float* out_b = out + 2 * NBATCH * MAXOBJ;
    if (tid < MAXOBJ)     { out_s[b * MAXOBJ + tid] = -1.f; out_c[b * MAXOBJ + tid] = -1.f; }
    if (tid < MAXOBJ * 4) out_b[b * MAXOBJ * 4 + tid] = 0.f;
    __syncthreads();
    if (tid < TOPN) {
        u64 kw = ~removed_sh[tid >> 6];       // keep-word (invalid already removed)
        if ((kw >> (tid & 63)) & 1ull) {
            int rank = (int)wpref[tid >> 6] + (int)__popcll(kw & ((1ull << (tid & 63)) - 1ull));
            if (rank < MAXOBJ) {
                size_t o = (size_t)b * TOPN + tid;
                out_s[b * MAXOBJ + rank] = tscore[o];
                out_c[b * MAXOBJ + rank] = tcls[o];
                ((float4*)out_b)[b * MAXOBJ + rank] = tbox[o];
            }
        }
    }
}

// -------------------------------------------------------------------------
// Workspace layout (bytes), total 4,226,176.  Nothing needs pre-zeroing:
//   keys    u32 [16][21824]     @ 0
//   clsidx  i32 [16][21824]     @ 1,396,736
//   tscore  f32 [16][1000]      @ 2,793,472
//   tcls    f32 [16][1000]      @ 2,857,472
//   tbox    f4  [16][1000]      @ 2,921,472
//   sup     u64 [16][1000][16]  @ 3,177,472  (iou output; clobbers candbuf)
//   candbuf u64 [16][8192]      @ 3,177,472  (dead after rank)
//   params  u32 [16][2]         @ 4,226,048  {M, target}
// -------------------------------------------------------------------------
extern "C" void kernel_launch(void* const* d_in, const int* in_sizes, int n_in,
                              void* d_out, int out_size, void* d_ws, size_t ws_size,
                              hipStream_t stream) {
    (void)in_sizes; (void)n_in; (void)out_size; (void)ws_size;
    const float* cls[5]; const float* reg[5]; const float* ctr[5];
    for (int l = 0; l < 5; ++l) {
        cls[l] = (const float*)d_in[4 * l + 0];
        reg[l] = (const float*)d_in[4 * l + 1];
        ctr[l] = (const float*)d_in[4 * l + 2];
    }
    char* w = (char*)d_ws;
    u32*    keys   = (u32*)(w + 0);
    int*    clsidx = (int*)(w + 1396736);
    float*  tscore = (float*)(w + 2793472);
    float*  tcls   = (float*)(w + 2857472);
    float4* tbox   = (float4*)(w + 2921472);
    u64*    sup    = (u64*)(w + 3177472);
    u64*    candbuf= (u64*)(w + 3177472);
    u32*    params = (u32*)(w + 4226048);

    decode_kernel<<<dim3((NTOT + 255) / 256, NBATCH), 256, 0, stream>>>(
        cls[0], cls[1], cls[2], cls[3], cls[4],
        ctr[0], ctr[1], ctr[2], ctr[3], ctr[4],
        keys, clsidx);
    pivot_gather_kernel<<<NBATCH, 1024, 0, stream>>>(keys, candbuf, params,
                                                     tscore, tcls, tbox);
    rank_kernel<<<dim3(8, NBATCH), 256, 0, stream>>>(candbuf, params, clsidx,
                                                     reg[0], reg[1], reg[2], reg[3], reg[4],
                                                     tscore, tcls, tbox);
    iou_kernel<<<dim3(TOPN / 4, NBATCH), 256, 0, stream>>>(tbox, sup);
    finalize_kernel<<<NBATCH, 1024, 0, stream>>>(tscore, tcls, tbox, sup, (float*)d_out);
}

// Round 7
// 271.063 us; speedup vs baseline: 1.1045x; 1.0186x over previous
//
#include <hip/hip_runtime.h>
#include <stdint.h>

typedef unsigned int u32;
typedef unsigned long long u64;

#define NTOT 21824   // 128*128 + 64*64 + 32*32 + 16*16 + 8*8 = 341*64
#define NBATCH 16
#define TOPN 1000
#define MAXOBJ 100
#define CAPC 8192      // global candidate buffer capacity per batch
#define BINBASE 15616  // = 122 << 7 : first populated fine bin (score > 0.05 => exp >= 122)
#define NBINS 1024     // 768 real bins (exp 122..127 x 7 mantissa bits), padded

// -------------------------------------------------------------------------
// Stage 1: decode (argmax over 80 classes + score key).  Pure streaming,
// no LDS, no atomics.  Quad-per-location; each quad handles TWO locations
// (loc0, loc0+64): 10 dwordx4 + 2 ctr loads in flight per lane.  2-deep
// is the harness-verified sweet spot (r4, < 48.9 us): 4-deep (r6) carried
// 80+ data VGPRs -> fewer resident waves -> WORSE latency hiding for this
// latency-bound kernel (r4 269.6 -> r6 276.1 with 4-deep the only decode
// change).  Level boundaries are multiples of 64 => each half-block is
// level-uniform; only the last block's second half is invalid.
// -------------------------------------------------------------------------
__device__ __forceinline__ void locate(
    int b, int loc,
    const float* __restrict__ cls0, const float* __restrict__ cls1,
    const float* __restrict__ cls2, const float* __restrict__ cls3,
    const float* __restrict__ cls4,
    const float* __restrict__ ctr0, const float* __restrict__ ctr1,
    const float* __restrict__ ctr2, const float* __restrict__ ctr3,
    const float* __restrict__ ctr4,
    const float*& cp, const float*& tp)
{
    if (loc < 16384)      { size_t o = (size_t)b*16384 + loc;          cp = cls0 + o*80; tp = ctr0 + o; }
    else if (loc < 20480) { size_t o = (size_t)b*4096  + (loc-16384);  cp = cls1 + o*80; tp = ctr1 + o; }
    else if (loc < 21504) { size_t o = (size_t)b*1024  + (loc-20480);  cp = cls2 + o*80; tp = ctr2 + o; }
    else if (loc < 21760) { size_t o = (size_t)b*256   + (loc-21504);  cp = cls3 + o*80; tp = ctr3 + o; }
    else                  { size_t o = (size_t)b*64    + (loc-21760);  cp = cls4 + o*80; tp = ctr4 + o; }
}

__global__ __launch_bounds__(256) void decode_kernel(
    const float* __restrict__ cls0, const float* __restrict__ cls1,
    const float* __restrict__ cls2, const float* __restrict__ cls3,
    const float* __restrict__ cls4,
    const float* __restrict__ ctr0, const float* __restrict__ ctr1,
    const float* __restrict__ ctr2, const float* __restrict__ ctr3,
    const float* __restrict__ ctr4,
    u32* __restrict__ keys, int* __restrict__ clsidx)
{
    int tid = threadIdx.x;
    int g = tid >> 2, j = tid & 3;          // quad index, quad sub-lane
    int b = blockIdx.y;
    int loc0 = blockIdx.x * 128 + g;        // always < NTOT (grid sized so)
    int loc1 = loc0 + 64;
    bool v1 = (loc1 < NTOT);                // uniform across the block

    const float *cp0, *tp0, *cp1, *tp1;
    locate(b, loc0, cls0, cls1, cls2, cls3, cls4, ctr0, ctr1, ctr2, ctr3, ctr4, cp0, tp0);
    locate(b, v1 ? loc1 : loc0, cls0, cls1, cls2, cls3, cls4, ctr0, ctr1, ctr2, ctr3, ctr4, cp1, tp1);

    const float4* c40 = (const float4*)cp0;
    const float4* c41 = (const float4*)cp1;
    float4 a0[5], a1[5];
#pragma unroll
    for (int q = 0; q < 5; ++q) a0[q] = c40[j + 4*q];
#pragma unroll
    for (int q = 0; q < 5; ++q) a1[q] = c41[j + 4*q];
    float t0v = *tp0;
    float t1v = *tp1;

    float maxv0 = -1.0f; int arg0 = 0;
    float maxv1 = -1.0f; int arg1 = 0;
#pragma unroll
    for (int q = 0; q < 5; ++q) {
        float4 v = a0[q];
        int ch = 16*q + 4*j;
        if (v.x > maxv0) { maxv0 = v.x; arg0 = ch;     }
        if (v.y > maxv0) { maxv0 = v.y; arg0 = ch + 1; }
        if (v.z > maxv0) { maxv0 = v.z; arg0 = ch + 2; }
        if (v.w > maxv0) { maxv0 = v.w; arg0 = ch + 3; }
    }
#pragma unroll
    for (int q = 0; q < 5; ++q) {
        float4 v = a1[q];
        int ch = 16*q + 4*j;
        if (v.x > maxv1) { maxv1 = v.x; arg1 = ch;     }
        if (v.y > maxv1) { maxv1 = v.y; arg1 = ch + 1; }
        if (v.z > maxv1) { maxv1 = v.z; arg1 = ch + 2; }
        if (v.w > maxv1) { maxv1 = v.w; arg1 = ch + 3; }
    }
    // quad reduction, exact first-max tie-break (lowest channel wins)
#pragma unroll
    for (int d = 1; d <= 2; d <<= 1) {
        float ov = __shfl_xor(maxv0, d);
        int   oa = __shfl_xor(arg0, d);
        if (ov > maxv0 || (ov == maxv0 && oa < arg0)) { maxv0 = ov; arg0 = oa; }
        float ow = __shfl_xor(maxv1, d);
        int   ob = __shfl_xor(arg1, d);
        if (ow > maxv1 || (ow == maxv1 && ob < arg1)) { maxv1 = ow; arg1 = ob; }
    }
    if (j == 0) {
        float score0 = sqrtf(maxv0 * t0v);   // correctly-rounded fp32 sqrt
        u32 key0 = (score0 > 0.05f) ? (__float_as_uint(score0) | 0x80000000u) : 0u;
        size_t o0 = (size_t)b * NTOT + loc0;
        keys[o0] = key0;
        clsidx[o0] = arg0;
        if (v1) {
            float score1 = sqrtf(maxv1 * t1v);
            u32 key1 = (score1 > 0.05f) ? (__float_as_uint(score1) | 0x80000000u) : 0u;
            size_t o1 = (size_t)b * NTOT + loc1;
            keys[o1] = key1;
            clsidx[o1] = arg1;
        }
    }
}

// -------------------------------------------------------------------------
// Stage 2: fused pivot + gather.  1 block/batch, 1024 thr.  O(N) passes
// ONLY (r5 lesson: the O(M^2) rank must stay out of 16-block kernels).
//  - pass A (keys, L2-hot): 1024-bin LDS histogram of fine bin
//    ((key>>16)&0x7FFF)-BINBASE; score in (0.05,1] => bin in [0,768).
//  - block suffix scan (1 bin/thread) locates exact pivot bin (r4-verified).
//  - pass B: compact all keys >= P into GLOBAL candbuf (LDS counter,
//    r5-verified ballot code).  M ~= target + ~170 << CAPC.
//  - writes output defaults.  params[2b] = {M, target}.
// -------------------------------------------------------------------------
__global__ __launch_bounds__(1024) void pivot_gather_kernel(
    const u32* __restrict__ keys, u64* __restrict__ candbuf, u32* __restrict__ params,
    float* __restrict__ tscore, float* __restrict__ tcls, float4* __restrict__ tbox)
{
    __shared__ u32 shist[NBINS];
    __shared__ u32 s_wtot[16];
    __shared__ int s_tf;
    __shared__ u32 s_cnt;
    int b = blockIdx.x, tid = threadIdx.x;
    int lane = tid & 63, wave = tid >> 6;
    const u32* kb = keys + (size_t)b * NTOT;

    for (int i = tid; i < TOPN; i += 1024) {
        size_t o = (size_t)b * TOPN + i;
        tscore[o] = -1.0f; tcls[o] = -1.0f;
        tbox[o] = make_float4(0.f, 0.f, 0.f, 0.f);
    }
    shist[tid] = 0;
    if (tid == 0) { s_tf = -1; s_cnt = 0; }
    __syncthreads();

    // ---- pass A: histogram ----
    for (int i = tid; i < NTOT; i += 1024) {
        u32 k = kb[i];
        if (k) {
            int v = (int)((k >> 16) & 0x7FFFu) - BINBASE;
            v = v < 0 ? 0 : (v > NBINS - 1 ? NBINS - 1 : v);
            atomicAdd(&shist[v], 1u);
        }
    }
    __syncthreads();

    // ---- block-wide inclusive suffix scan, 1 bin per thread ----
    u32 h = shist[tid];
    u32 x = h;
#pragma unroll
    for (int off = 1; off < 64; off <<= 1) {
        u32 y = __shfl_down(x, off);
        if (lane + off < 64) x += y;
    }
    if (lane == 0) s_wtot[wave] = x;
    __syncthreads();
    u32 wsuf = 0, tot = 0;
    for (int w2 = 0; w2 < 16; ++w2) { u32 v = s_wtot[w2]; tot += v; if (w2 > wave) wsuf += v; }
    u32 suffix_incl = x + wsuf;          // #keys with bin >= tid
    u32 target = (tot < TOPN) ? tot : TOPN;

    if (target > 0 && suffix_incl >= target) atomicMax(&s_tf, tid);
    __syncthreads();
    u32 P;
    {
        int t0 = s_tf;                   // uniform: tot/target uniform, s_tf shared
        if (target == 0)        P = 0xFFFFFFFFu;   // nothing passes
        else if (tot <= TOPN)   P = 1u;            // take every valid key
        else                    P = ((u32)(t0 + BINBASE) << 16) | 0x80000000u;
    }

    // ---- pass B: compact keys >= P into global candbuf ----
    for (int base = 0; base < NTOT; base += 1024) {
        int i = base + tid;
        u32 k = (i < NTOT) ? kb[i] : 0u;
        bool pass = (k != 0u) && (k >= P);
        u64 mask = __ballot(pass);
        u32 wbase = 0;
        if (lane == 0 && mask) wbase = atomicAdd(&s_cnt, (u32)__popcll(mask));
        wbase = __shfl(wbase, 0);
        if (pass) {
            u32 pos = wbase + (u32)__popcll(mask & ((1ull << lane) - 1ull));
            if (pos < CAPC) candbuf[(size_t)b * CAPC + pos] = ((u64)k << 32) | (u32)(~i);
        }
    }
    __syncthreads();
    if (tid == 0) {
        u32 M = s_cnt; if (M > CAPC) M = CAPC;
        params[2 * b] = M;
        params[2 * b + 1] = target;
    }
}

// -------------------------------------------------------------------------
// Stage 3: rank-by-count + scatter, DISTRIBUTED (8 blocks x 16 batches so
// the O(M^2) count runs on 128 blocks, ~1 wave-iteration each).  Box
// decode (reg read + trunc) for the <= CAPC candidates only (exact same
// fp32 ops as the reference; px,py recomputed exactly).
// -------------------------------------------------------------------------
__global__ __launch_bounds__(256) void rank_kernel(
    const u64* __restrict__ candbuf, const u32* __restrict__ params,
    const int* __restrict__ clsidx,
    const float* __restrict__ reg0, const float* __restrict__ reg1,
    const float* __restrict__ reg2, const float* __restrict__ reg3,
    const float* __restrict__ reg4,
    float* __restrict__ tscore, float* __restrict__ tcls, float4* __restrict__ tbox)
{
    int b = blockIdx.y;
    int lane = threadIdx.x & 63;
    u32 M = params[2 * b];
    u32 target = params[2 * b + 1];
    const u64* cb = candbuf + (size_t)b * CAPC;
    u32 Mr = (M + 63u) & ~63u;

    u32 wbase0 = blockIdx.x * 256 + (threadIdx.x & ~63u);
    for (u32 base = wbase0; base < M; base += 8 * 256) {   // uniform per wave
        u32 i0 = base + lane;
        bool val = (i0 < M);
        u64 e = val ? cb[i0] : ~0ull;
        u32 r = 0;
        for (u32 c0 = 0; c0 < Mr; c0 += 64) {
            u32 j = c0 + lane;
            u64 v = (j < M) ? cb[j] : 0ull;   // 0 is never > any candidate
            u32 vlo = (u32)v, vhi = (u32)(v >> 32);
#pragma unroll
            for (int s = 0; s < 64; ++s) {
                u32 lo = (u32)__builtin_amdgcn_readlane((int)vlo, s);
                u32 hi = (u32)__builtin_amdgcn_readlane((int)vhi, s);
                u64 vj = ((u64)hi << 32) | lo;
                r += (vj > e) ? 1u : 0u;
            }
        }
        if (val && r < target) {
            u32 k = (u32)(e >> 32);
            u32 loc = ~(u32)e;
            const float* rp; float st; u32 li; int wsh;
            if (loc < 16384u)      { li = loc;          wsh = 7; st = 8.f;   rp = reg0 + ((size_t)b*16384 + li)*4; }
            else if (loc < 20480u) { li = loc - 16384u; wsh = 6; st = 16.f;  rp = reg1 + ((size_t)b*4096  + li)*4; }
            else if (loc < 21504u) { li = loc - 20480u; wsh = 5; st = 32.f;  rp = reg2 + ((size_t)b*1024  + li)*4; }
            else if (loc < 21760u) { li = loc - 21504u; wsh = 4; st = 64.f;  rp = reg3 + ((size_t)b*256   + li)*4; }
            else                   { li = loc - 21760u; wsh = 3; st = 128.f; rp = reg4 + ((size_t)b*64    + li)*4; }
            u32 wx = li & ((1u << wsh) - 1u);
            u32 hy = li >> wsh;
            float px = ((float)wx + 0.5f) * st;
            float py = ((float)hy + 0.5f) * st;
            float4 rg = *(const float4*)rp;
            float4 bx;
            bx.x = truncf(px - rg.x); bx.y = truncf(py - rg.y);
            bx.z = truncf(px + rg.z); bx.w = truncf(py + rg.w);
            size_t src = (size_t)b * NTOT + loc;
            size_t o = (size_t)b * TOPN + r;
            tscore[o] = __uint_as_float(k & 0x7FFFFFFFu);
            tcls[o] = (float)clsidx[src];
            tbox[o] = bx;
        }
    }
}

// -------------------------------------------------------------------------
// Stage 4: suppression-bit matrix.  4 rows per 256-thread block.
// -------------------------------------------------------------------------
__global__ __launch_bounds__(256) void iou_kernel(
    const float4* __restrict__ tbox, u64* __restrict__ sup)
{
    __shared__ float4 sbox[TOPN];
    int b = blockIdx.y;
    int tid = threadIdx.x, lane = tid & 63, wave = tid >> 6;
    const float4* tb = tbox + (size_t)b * TOPN;
    for (int i = tid; i < TOPN; i += 256) sbox[i] = tb[i];
    __syncthreads();
    int i = blockIdx.x * 4 + wave;
    float4 bi = sbox[i];
    float areai = fmaxf((bi.z - bi.x) * (bi.w - bi.y), 0.0001f);
    u64* row = sup + ((size_t)b * TOPN + i) * 16;
#pragma unroll
    for (int w = 0; w < 16; ++w) {
        int col = w * 64 + lane;
        bool bit = false;
        if (col < TOPN) {
            float4 bj = sbox[col];
            float areaj = fmaxf((bj.z - bj.x) * (bj.w - bj.y), 0.0001f);
            float tlx = fmaxf(bi.x, bj.x), tly = fmaxf(bi.y, bj.y);
            float brx = fminf(bi.z, bj.z), bry = fminf(bi.w, bj.w);
            float ow = fmaxf(brx - tlx, 0.f), oh = fmaxf(bry - tly, 0.f);
            float inter = ow * oh;
            float uni = fmaxf(areai + areaj - inter, 0.0001f);
            bit = (col > i) && (inter / uni >= 0.6f);
        }
        u64 m = __ballot(bit);
        if (lane == 0) row[w] = m;
    }
}

// -------------------------------------------------------------------------
// Stage 5: greedy serial scan + popcount-rank output.
// -------------------------------------------------------------------------
#define CHROWS 128
#define NCHUNK 8

__global__ __launch_bounds__(1024) void finalize_kernel(
    const float* __restrict__ tscore, const float* __restrict__ tcls,
    const float4* __restrict__ tbox, const u64* __restrict__ sup,
    float* __restrict__ out)
{
    __shared__ u64 mat[2][CHROWS * 16];
    __shared__ u32 validsh[TOPN];
    __shared__ u64 removed_sh[16];
    __shared__ u32 wpref[17];
    int b = blockIdx.x, tid = threadIdx.x;
    int wave = tid >> 6, lane = tid & 63;

    for (int i = tid; i < TOPN; i += 1024)
        validsh[i] = (tscore[(size_t)b * TOPN + i] > 0.05f) ? 1u : 0u;

    const u64* supb = sup + (size_t)b * TOPN * 16;
    for (int idx = tid; idx < CHROWS * 16; idx += 1024)
        mat[0][idx] = supb[idx];
    __syncthreads();

    u64 my = 0;
    if (wave == 0) {
#pragma unroll
        for (int w2 = 0; w2 < 16; ++w2) {
            int i = w2 * 64 + lane;
            bool v = (i < TOPN) ? (validsh[i] != 0) : false;
            u64 m = __ballot(v);
            if (lane == w2) my = ~m;
        }
    }

    for (int chunk = 0; chunk < NCHUNK; ++chunk) {
        if (wave > 0 && chunk + 1 < NCHUNK) {
            int nr = (chunk + 1 == NCHUNK - 1) ? (TOPN - (NCHUNK - 1) * CHROWS) : CHROWS;
            const u64* src = supb + (size_t)(chunk + 1) * CHROWS * 16;
            u64* dst = mat[(chunk + 1) & 1];
            for (int idx = tid - 64; idx < nr * 16; idx += 960)
                dst[idx] = src[idx];
        }
        if (wave == 0) {
            int r0 = chunk * CHROWS;
            int rows = (chunk == NCHUNK - 1) ? (TOPN - r0) : CHROWS;
            int lw = lane & 15;
            const u64* M = mat[chunk & 1];
            for (int sub = 0; sub < rows; sub += 64) {
                int w2 = (r0 + sub) >> 6;
                u64 cur = __shfl(my, w2);
                int nsub = rows - sub; if (nsub > 64) nsub = 64;
                const u64* R = M + sub * 16;
                int ngrp = nsub >> 3;
                u64 cme[8], cww[8];
#pragma unroll
                for (int g = 0; g < 8; ++g) { cme[g] = R[g*16 + lw]; cww[g] = R[g*16 + w2]; }
                for (int grp = 0; grp < ngrp; ++grp) {
                    u64 nme[8] = {0,0,0,0,0,0,0,0}, nww[8] = {0,0,0,0,0,0,0,0};
                    if (grp + 1 < ngrp) {
                        const u64* Rn = R + (grp + 1) * 128;
#pragma unroll
                        for (int g = 0; g < 8; ++g) { nme[g] = Rn[g*16 + lw]; nww[g] = Rn[g*16 + w2]; }
                    }
#pragma unroll
                    for (int g = 0; g < 8; ++g) {
                        int u = grp * 8 + g;
                        u64 bit = (cur >> u) & 1ull;
                        u64 act = bit - 1ull;
                        cur |= cww[g] & act;
                        my  |= cme[g] & act;
                    }
#pragma unroll
                    for (int g = 0; g < 8; ++g) { cme[g] = nme[g]; cww[g] = nww[g]; }
                }
            }
        }
        __syncthreads();
    }
    if (wave == 0) {
        if (lane < 16) removed_sh[lane] = my;
        u32 pc = (lane < 16) ? (u32)__popcll(~my) : 0u;
#pragma unroll
        for (int off = 1; off < 16; off <<= 1) {
            u32 y = __shfl_up(pc, off);
            if (lane >= off) pc += y;
        }
        if (lane < 16) wpref[lane + 1] = pc;
        if (lane == 0) wpref[0] = 0;
    }
    __syncthreads();

    float* out_s = out;
    float* out_c = out + NBATCH * MAXOBJ;
    float* out_b = out + 2 * NBATCH * MAXOBJ;
    if (tid < MAXOBJ)     { out_s[b * MAXOBJ + tid] = -1.f; out_c[b * MAXOBJ + tid] = -1.f; }
    if (tid < MAXOBJ * 4) out_b[b * MAXOBJ * 4 + tid] = 0.f;
    __syncthreads();
    if (tid < TOPN) {
        u64 kw = ~removed_sh[tid >> 6];       // keep-word (invalid already removed)
        if ((kw >> (tid & 63)) & 1ull) {
            int rank = (int)wpref[tid >> 6] + (int)__popcll(kw & ((1ull << (tid & 63)) - 1ull));
            if (rank < MAXOBJ) {
                size_t o = (size_t)b * TOPN + tid;
                out_s[b * MAXOBJ + rank] = tscore[o];
                out_c[b * MAXOBJ + rank] = tcls[o];
                ((float4*)out_b)[b * MAXOBJ + rank] = tbox[o];
            }
        }
    }
}

// -------------------------------------------------------------------------
// Workspace layout (bytes), total 4,226,176.  Nothing needs pre-zeroing:
//   keys    u32 [16][21824]     @ 0
//   clsidx  i32 [16][21824]     @ 1,396,736
//   tscore  f32 [16][1000]      @ 2,793,472
//   tcls    f32 [16][1000]      @ 2,857,472
//   tbox    f4  [16][1000]      @ 2,921,472
//   sup     u64 [16][1000][16]  @ 3,177,472  (iou output; clobbers candbuf)
//   candbuf u64 [16][8192]      @ 3,177,472  (dead after rank)
//   params  u32 [16][2]         @ 4,226,048  {M, target}
// -------------------------------------------------------------------------
extern "C" void kernel_launch(void* const* d_in, const int* in_sizes, int n_in,
                              void* d_out, int out_size, void* d_ws, size_t ws_size,
                              hipStream_t stream) {
    (void)in_sizes; (void)n_in; (void)out_size; (void)ws_size;
    const float* cls[5]; const float* reg[5]; const float* ctr[5];
    for (int l = 0; l < 5; ++l) {
        cls[l] = (const float*)d_in[4 * l + 0];
        reg[l] = (const float*)d_in[4 * l + 1];
        ctr[l] = (const float*)d_in[4 * l + 2];
    }
    char* w = (char*)d_ws;
    u32*    keys   = (u32*)(w + 0);
    int*    clsidx = (int*)(w + 1396736);
    float*  tscore = (float*)(w + 2793472);
    float*  tcls   = (float*)(w + 2857472);
    float4* tbox   = (float4*)(w + 2921472);
    u64*    sup    = (u64*)(w + 3177472);
    u64*    candbuf= (u64*)(w + 3177472);
    u32*    params = (u32*)(w + 4226048);

    decode_kernel<<<dim3((NTOT + 127) / 128, NBATCH), 256, 0, stream>>>(
        cls[0], cls[1], cls[2], cls[3], cls[4],
        ctr[0], ctr[1], ctr[2], ctr[3], ctr[4],
        keys, clsidx);
    pivot_gather_kernel<<<NBATCH, 1024, 0, stream>>>(keys, candbuf, params,
                                                     tscore, tcls, tbox);
    rank_kernel<<<dim3(8, NBATCH), 256, 0, stream>>>(candbuf, params, clsidx,
                                                     reg[0], reg[1], reg[2], reg[3], reg[4],
                                                     tscore, tcls, tbox);
    iou_kernel<<<dim3(TOPN / 4, NBATCH), 256, 0, stream>>>(tbox, sup);
    finalize_kernel<<<NBATCH, 1024, 0, stream>>>(tscore, tcls, tbox, sup, (float*)d_out);
}

// Round 8
// 238.790 us; speedup vs baseline: 1.2538x; 1.1351x over previous
//
#include <hip/hip_runtime.h>
#include <stdint.h>

typedef unsigned int u32;
typedef unsigned long long u64;

#define NTOT 21824   // 128*128 + 64*64 + 32*32 + 16*16 + 8*8 = 341*64
#define NBATCH 16
#define TOPN 1000
#define MAXOBJ 100
#define CAPC 8192      // global candidate buffer capacity per batch
#define BINBASE 15616  // = 122 << 7 : first populated fine bin (score > 0.05 => exp >= 122)
#define NBINS 1024     // 768 real bins (exp 122..127 x 7 mantissa bits), padded

// -------------------------------------------------------------------------
// Stage 1: decode (argmax over 80 classes + score key).  Pure streaming,
// no LDS, no atomics.  Quad-per-location; each quad handles TWO locations
// (loc0, loc0+64): 10 dwordx4 + 2 ctr loads in flight per lane.  2-deep
// is the harness-verified sweet spot (r4): 4-deep (r6) cost occupancy and
// regressed.  Level boundaries are multiples of 64 => each half-block is
// level-uniform; only the last block's second half is invalid.
// -------------------------------------------------------------------------
__device__ __forceinline__ void locate(
    int b, int loc,
    const float* __restrict__ cls0, const float* __restrict__ cls1,
    const float* __restrict__ cls2, const float* __restrict__ cls3,
    const float* __restrict__ cls4,
    const float* __restrict__ ctr0, const float* __restrict__ ctr1,
    const float* __restrict__ ctr2, const float* __restrict__ ctr3,
    const float* __restrict__ ctr4,
    const float*& cp, const float*& tp)
{
    if (loc < 16384)      { size_t o = (size_t)b*16384 + loc;          cp = cls0 + o*80; tp = ctr0 + o; }
    else if (loc < 20480) { size_t o = (size_t)b*4096  + (loc-16384);  cp = cls1 + o*80; tp = ctr1 + o; }
    else if (loc < 21504) { size_t o = (size_t)b*1024  + (loc-20480);  cp = cls2 + o*80; tp = ctr2 + o; }
    else if (loc < 21760) { size_t o = (size_t)b*256   + (loc-21504);  cp = cls3 + o*80; tp = ctr3 + o; }
    else                  { size_t o = (size_t)b*64    + (loc-21760);  cp = cls4 + o*80; tp = ctr4 + o; }
}

__global__ __launch_bounds__(256) void decode_kernel(
    const float* __restrict__ cls0, const float* __restrict__ cls1,
    const float* __restrict__ cls2, const float* __restrict__ cls3,
    const float* __restrict__ cls4,
    const float* __restrict__ ctr0, const float* __restrict__ ctr1,
    const float* __restrict__ ctr2, const float* __restrict__ ctr3,
    const float* __restrict__ ctr4,
    u32* __restrict__ keys, int* __restrict__ clsidx)
{
    int tid = threadIdx.x;
    int g = tid >> 2, j = tid & 3;          // quad index, quad sub-lane
    int b = blockIdx.y;
    int loc0 = blockIdx.x * 128 + g;        // always < NTOT (grid sized so)
    int loc1 = loc0 + 64;
    bool v1 = (loc1 < NTOT);                // uniform across the block

    const float *cp0, *tp0, *cp1, *tp1;
    locate(b, loc0, cls0, cls1, cls2, cls3, cls4, ctr0, ctr1, ctr2, ctr3, ctr4, cp0, tp0);
    locate(b, v1 ? loc1 : loc0, cls0, cls1, cls2, cls3, cls4, ctr0, ctr1, ctr2, ctr3, ctr4, cp1, tp1);

    const float4* c40 = (const float4*)cp0;
    const float4* c41 = (const float4*)cp1;
    float4 a0[5], a1[5];
#pragma unroll
    for (int q = 0; q < 5; ++q) a0[q] = c40[j + 4*q];
#pragma unroll
    for (int q = 0; q < 5; ++q) a1[q] = c41[j + 4*q];
    float t0v = *tp0;
    float t1v = *tp1;

    float maxv0 = -1.0f; int arg0 = 0;
    float maxv1 = -1.0f; int arg1 = 0;
#pragma unroll
    for (int q = 0; q < 5; ++q) {
        float4 v = a0[q];
        int ch = 16*q + 4*j;
        if (v.x > maxv0) { maxv0 = v.x; arg0 = ch;     }
        if (v.y > maxv0) { maxv0 = v.y; arg0 = ch + 1; }
        if (v.z > maxv0) { maxv0 = v.z; arg0 = ch + 2; }
        if (v.w > maxv0) { maxv0 = v.w; arg0 = ch + 3; }
    }
#pragma unroll
    for (int q = 0; q < 5; ++q) {
        float4 v = a1[q];
        int ch = 16*q + 4*j;
        if (v.x > maxv1) { maxv1 = v.x; arg1 = ch;     }
        if (v.y > maxv1) { maxv1 = v.y; arg1 = ch + 1; }
        if (v.z > maxv1) { maxv1 = v.z; arg1 = ch + 2; }
        if (v.w > maxv1) { maxv1 = v.w; arg1 = ch + 3; }
    }
    // quad reduction, exact first-max tie-break (lowest channel wins)
#pragma unroll
    for (int d = 1; d <= 2; d <<= 1) {
        float ov = __shfl_xor(maxv0, d);
        int   oa = __shfl_xor(arg0, d);
        if (ov > maxv0 || (ov == maxv0 && oa < arg0)) { maxv0 = ov; arg0 = oa; }
        float ow = __shfl_xor(maxv1, d);
        int   ob = __shfl_xor(arg1, d);
        if (ow > maxv1 || (ow == maxv1 && ob < arg1)) { maxv1 = ow; arg1 = ob; }
    }
    if (j == 0) {
        float score0 = sqrtf(maxv0 * t0v);   // correctly-rounded fp32 sqrt
        u32 key0 = (score0 > 0.05f) ? (__float_as_uint(score0) | 0x80000000u) : 0u;
        size_t o0 = (size_t)b * NTOT + loc0;
        keys[o0] = key0;
        clsidx[o0] = arg0;
        if (v1) {
            float score1 = sqrtf(maxv1 * t1v);
            u32 key1 = (score1 > 0.05f) ? (__float_as_uint(score1) | 0x80000000u) : 0u;
            size_t o1 = (size_t)b * NTOT + loc1;
            keys[o1] = key1;
            clsidx[o1] = arg1;
        }
    }
}

// -------------------------------------------------------------------------
// Stage 2: fused pivot + gather.  1 block/batch, 1024 thr.  O(N) passes
// ONLY (r5 lesson: the O(M^2) rank must stay out of 16-block kernels).
//  - pass A (keys, L2-hot): 1024-bin LDS histogram of fine bin
//    ((key>>16)&0x7FFF)-BINBASE; score in (0.05,1] => bin in [0,768).
//  - block suffix scan (1 bin/thread) locates exact pivot bin (r4-verified).
//  - pass B: compact all keys >= P into GLOBAL candbuf (LDS counter,
//    r5-verified ballot code).  M ~= target + ~170 << CAPC.
//  - writes output defaults.  params[2b] = {M, target}.
// -------------------------------------------------------------------------
__global__ __launch_bounds__(1024) void pivot_gather_kernel(
    const u32* __restrict__ keys, u64* __restrict__ candbuf, u32* __restrict__ params,
    float* __restrict__ tscore, float* __restrict__ tcls, float4* __restrict__ tbox)
{
    __shared__ u32 shist[NBINS];
    __shared__ u32 s_wtot[16];
    __shared__ int s_tf;
    __shared__ u32 s_cnt;
    int b = blockIdx.x, tid = threadIdx.x;
    int lane = tid & 63, wave = tid >> 6;
    const u32* kb = keys + (size_t)b * NTOT;

    for (int i = tid; i < TOPN; i += 1024) {
        size_t o = (size_t)b * TOPN + i;
        tscore[o] = -1.0f; tcls[o] = -1.0f;
        tbox[o] = make_float4(0.f, 0.f, 0.f, 0.f);
    }
    shist[tid] = 0;
    if (tid == 0) { s_tf = -1; s_cnt = 0; }
    __syncthreads();

    // ---- pass A: histogram ----
    for (int i = tid; i < NTOT; i += 1024) {
        u32 k = kb[i];
        if (k) {
            int v = (int)((k >> 16) & 0x7FFFu) - BINBASE;
            v = v < 0 ? 0 : (v > NBINS - 1 ? NBINS - 1 : v);
            atomicAdd(&shist[v], 1u);
        }
    }
    __syncthreads();

    // ---- block-wide inclusive suffix scan, 1 bin per thread ----
    u32 h = shist[tid];
    u32 x = h;
#pragma unroll
    for (int off = 1; off < 64; off <<= 1) {
        u32 y = __shfl_down(x, off);
        if (lane + off < 64) x += y;
    }
    if (lane == 0) s_wtot[wave] = x;
    __syncthreads();
    u32 wsuf = 0, tot = 0;
    for (int w2 = 0; w2 < 16; ++w2) { u32 v = s_wtot[w2]; tot += v; if (w2 > wave) wsuf += v; }
    u32 suffix_incl = x + wsuf;          // #keys with bin >= tid
    u32 target = (tot < TOPN) ? tot : TOPN;

    if (target > 0 && suffix_incl >= target) atomicMax(&s_tf, tid);
    __syncthreads();
    u32 P;
    {
        int t0 = s_tf;                   // uniform: tot/target uniform, s_tf shared
        if (target == 0)        P = 0xFFFFFFFFu;   // nothing passes
        else if (tot <= TOPN)   P = 1u;            // take every valid key
        else                    P = ((u32)(t0 + BINBASE) << 16) | 0x80000000u;
    }

    // ---- pass B: compact keys >= P into global candbuf ----
    for (int base = 0; base < NTOT; base += 1024) {
        int i = base + tid;
        u32 k = (i < NTOT) ? kb[i] : 0u;
        bool pass = (k != 0u) && (k >= P);
        u64 mask = __ballot(pass);
        u32 wbase = 0;
        if (lane == 0 && mask) wbase = atomicAdd(&s_cnt, (u32)__popcll(mask));
        wbase = __shfl(wbase, 0);
        if (pass) {
            u32 pos = wbase + (u32)__popcll(mask & ((1ull << lane) - 1ull));
            if (pos < CAPC) candbuf[(size_t)b * CAPC + pos] = ((u64)k << 32) | (u32)(~i);
        }
    }
    __syncthreads();
    if (tid == 0) {
        u32 M = s_cnt; if (M > CAPC) M = CAPC;
        params[2 * b] = M;
        params[2 * b + 1] = target;
    }
}

// -------------------------------------------------------------------------
// Stage 3: rank-by-count + scatter, DISTRIBUTED (8 blocks x 16 batches so
// the O(M^2) count runs on 128 blocks, ~1 wave-iteration each).  Box
// decode (reg read + trunc) for the <= CAPC candidates only (exact same
// fp32 ops as the reference; px,py recomputed exactly).
// -------------------------------------------------------------------------
__global__ __launch_bounds__(256) void rank_kernel(
    const u64* __restrict__ candbuf, const u32* __restrict__ params,
    const int* __restrict__ clsidx,
    const float* __restrict__ reg0, const float* __restrict__ reg1,
    const float* __restrict__ reg2, const float* __restrict__ reg3,
    const float* __restrict__ reg4,
    float* __restrict__ tscore, float* __restrict__ tcls, float4* __restrict__ tbox)
{
    int b = blockIdx.y;
    int lane = threadIdx.x & 63;
    u32 M = params[2 * b];
    u32 target = params[2 * b + 1];
    const u64* cb = candbuf + (size_t)b * CAPC;
    u32 Mr = (M + 63u) & ~63u;

    u32 wbase0 = blockIdx.x * 256 + (threadIdx.x & ~63u);
    for (u32 base = wbase0; base < M; base += 8 * 256) {   // uniform per wave
        u32 i0 = base + lane;
        bool val = (i0 < M);
        u64 e = val ? cb[i0] : ~0ull;
        u32 r = 0;
        for (u32 c0 = 0; c0 < Mr; c0 += 64) {
            u32 j = c0 + lane;
            u64 v = (j < M) ? cb[j] : 0ull;   // 0 is never > any candidate
            u32 vlo = (u32)v, vhi = (u32)(v >> 32);
#pragma unroll
            for (int s = 0; s < 64; ++s) {
                u32 lo = (u32)__builtin_amdgcn_readlane((int)vlo, s);
                u32 hi = (u32)__builtin_amdgcn_readlane((int)vhi, s);
                u64 vj = ((u64)hi << 32) | lo;
                r += (vj > e) ? 1u : 0u;
            }
        }
        if (val && r < target) {
            u32 k = (u32)(e >> 32);
            u32 loc = ~(u32)e;
            const float* rp; float st; u32 li; int wsh;
            if (loc < 16384u)      { li = loc;          wsh = 7; st = 8.f;   rp = reg0 + ((size_t)b*16384 + li)*4; }
            else if (loc < 20480u) { li = loc - 16384u; wsh = 6; st = 16.f;  rp = reg1 + ((size_t)b*4096  + li)*4; }
            else if (loc < 21504u) { li = loc - 20480u; wsh = 5; st = 32.f;  rp = reg2 + ((size_t)b*1024  + li)*4; }
            else if (loc < 21760u) { li = loc - 21504u; wsh = 4; st = 64.f;  rp = reg3 + ((size_t)b*256   + li)*4; }
            else                   { li = loc - 21760u; wsh = 3; st = 128.f; rp = reg4 + ((size_t)b*64    + li)*4; }
            u32 wx = li & ((1u << wsh) - 1u);
            u32 hy = li >> wsh;
            float px = ((float)wx + 0.5f) * st;
            float py = ((float)hy + 0.5f) * st;
            float4 rg = *(const float4*)rp;
            float4 bx;
            bx.x = truncf(px - rg.x); bx.y = truncf(py - rg.y);
            bx.z = truncf(px + rg.z); bx.w = truncf(py + rg.w);
            size_t src = (size_t)b * NTOT + loc;
            size_t o = (size_t)b * TOPN + r;
            tscore[o] = __uint_as_float(k & 0x7FFFFFFFu);
            tcls[o] = (float)clsidx[src];
            tbox[o] = bx;
        }
    }
}

// -------------------------------------------------------------------------
// Stage 4: suppression-bit matrix.  4 rows per 256-thread block.
// -------------------------------------------------------------------------
__global__ __launch_bounds__(256) void iou_kernel(
    const float4* __restrict__ tbox, u64* __restrict__ sup)
{
    __shared__ float4 sbox[TOPN];
    int b = blockIdx.y;
    int tid = threadIdx.x, lane = tid & 63, wave = tid >> 6;
    const float4* tb = tbox + (size_t)b * TOPN;
    for (int i = tid; i < TOPN; i += 256) sbox[i] = tb[i];
    __syncthreads();
    int i = blockIdx.x * 4 + wave;
    float4 bi = sbox[i];
    float areai = fmaxf((bi.z - bi.x) * (bi.w - bi.y), 0.0001f);
    u64* row = sup + ((size_t)b * TOPN + i) * 16;
#pragma unroll
    for (int w = 0; w < 16; ++w) {
        int col = w * 64 + lane;
        bool bit = false;
        if (col < TOPN) {
            float4 bj = sbox[col];
            float areaj = fmaxf((bj.z - bj.x) * (bj.w - bj.y), 0.0001f);
            float tlx = fmaxf(bi.x, bj.x), tly = fmaxf(bi.y, bj.y);
            float brx = fminf(bi.z, bj.z), bry = fminf(bi.w, bj.w);
            float ow = fmaxf(brx - tlx, 0.f), oh = fmaxf(bry - tly, 0.f);
            float inter = ow * oh;
            float uni = fmaxf(areai + areaj - inter, 0.0001f);
            bit = (col > i) && (inter / uni >= 0.6f);
        }
        u64 m = __ballot(bit);
        if (lane == 0) row[w] = m;
    }
}

// -------------------------------------------------------------------------
// Stage 5: greedy serial scan + popcount-rank output, with EARLY EXIT.
// Greedy NMS is strictly forward: after chunk c, rows < 128*(c+1) are
// final.  The output needs only the first MAXOBJ=100 keeps, so once the
// keep-count among finalized rows reaches 100, all later rows are
// irrelevant -> mark removed and stop (saves ~75-85% of the serial
// dependency chain when keeps are dense, which they are for this data).
// If total keeps < 100 the loop runs to completion (bit-identical).
// -------------------------------------------------------------------------
#define CHROWS 128
#define NCHUNK 8

__global__ __launch_bounds__(1024) void finalize_kernel(
    const float* __restrict__ tscore, const float* __restrict__ tcls,
    const float4* __restrict__ tbox, const u64* __restrict__ sup,
    float* __restrict__ out)
{
    __shared__ u64 mat[2][CHROWS * 16];
    __shared__ u32 validsh[TOPN];
    __shared__ u64 removed_sh[16];
    __shared__ u32 wpref[17];
    __shared__ int s_done;
    int b = blockIdx.x, tid = threadIdx.x;
    int wave = tid >> 6, lane = tid & 63;

    for (int i = tid; i < TOPN; i += 1024)
        validsh[i] = (tscore[(size_t)b * TOPN + i] > 0.05f) ? 1u : 0u;

    const u64* supb = sup + (size_t)b * TOPN * 16;
    for (int idx = tid; idx < CHROWS * 16; idx += 1024)
        mat[0][idx] = supb[idx];
    if (tid == 0) s_done = 0;
    __syncthreads();

    u64 my = 0;
    if (wave == 0) {
#pragma unroll
        for (int w2 = 0; w2 < 16; ++w2) {
            int i = w2 * 64 + lane;
            bool v = (i < TOPN) ? (validsh[i] != 0) : false;
            u64 m = __ballot(v);
            if (lane == w2) my = ~m;
        }
    }

    for (int chunk = 0; chunk < NCHUNK; ++chunk) {
        if (wave > 0 && chunk + 1 < NCHUNK) {
            int nr = (chunk + 1 == NCHUNK - 1) ? (TOPN - (NCHUNK - 1) * CHROWS) : CHROWS;
            const u64* src = supb + (size_t)(chunk + 1) * CHROWS * 16;
            u64* dst = mat[(chunk + 1) & 1];
            for (int idx = tid - 64; idx < nr * 16; idx += 960)
                dst[idx] = src[idx];
        }
        if (wave == 0) {
            int r0 = chunk * CHROWS;
            int rows = (chunk == NCHUNK - 1) ? (TOPN - r0) : CHROWS;
            int lw = lane & 15;
            const u64* M = mat[chunk & 1];
            for (int sub = 0; sub < rows; sub += 64) {
                int w2 = (r0 + sub) >> 6;
                u64 cur = __shfl(my, w2);
                int nsub = rows - sub; if (nsub > 64) nsub = 64;
                const u64* R = M + sub * 16;
                int ngrp = nsub >> 3;
                u64 cme[8], cww[8];
#pragma unroll
                for (int g = 0; g < 8; ++g) { cme[g] = R[g*16 + lw]; cww[g] = R[g*16 + w2]; }
                for (int grp = 0; grp < ngrp; ++grp) {
                    u64 nme[8] = {0,0,0,0,0,0,0,0}, nww[8] = {0,0,0,0,0,0,0,0};
                    if (grp + 1 < ngrp) {
                        const u64* Rn = R + (grp + 1) * 128;
#pragma unroll
                        for (int g = 0; g < 8; ++g) { nme[g] = Rn[g*16 + lw]; nww[g] = Rn[g*16 + w2]; }
                    }
#pragma unroll
                    for (int g = 0; g < 8; ++g) {
                        int u = grp * 8 + g;
                        u64 bit = (cur >> u) & 1ull;
                        u64 act = bit - 1ull;
                        cur |= cww[g] & act;
                        my  |= cme[g] & act;
                    }
#pragma unroll
                    for (int g = 0; g < 8; ++g) { cme[g] = nme[g]; cww[g] = nww[g]; }
                }
            }
            // early-exit check: keeps among FINALIZED words only
            int limw = (chunk == NCHUNK - 1) ? 16 : 2 * (chunk + 1);
            u32 pc = (lane < limw && lane < 16) ? (u32)__popcll(~my) : 0u;
#pragma unroll
            for (int off = 1; off < 16; off <<= 1) pc += __shfl_xor(pc, off);
            if (lane == 0 && pc >= MAXOBJ) s_done = limw;
        }
        __syncthreads();
        if (s_done) break;
    }
    if (wave == 0) {
        int limw = s_done ? s_done : 16;
        u64 myf = (lane < limw) ? my : ~0ull;   // unfinalized rows -> removed
        if (lane < 16) removed_sh[lane] = myf;
        u32 pc = (lane < 16) ? (u32)__popcll(~myf) : 0u;
#pragma unroll
        for (int off = 1; off < 16; off <<= 1) {
            u32 y = __shfl_up(pc, off);
            if (lane >= off) pc += y;
        }
        if (lane < 16) wpref[lane + 1] = pc;
        if (lane == 0) wpref[0] = 0;
    }
    __syncthreads();

    float* out_s = out;
    float* out_c = out + NBATCH * MAXOBJ;
    float* out_b = out + 2 * NBATCH * MAXOBJ;
    if (tid < MAXOBJ)     { out_s[b * MAXOBJ + tid] = -1.f; out_c[b * MAXOBJ + tid] = -1.f; }
    if (tid < MAXOBJ * 4) out_b[b * MAXOBJ * 4 + tid] = 0.f;
    __syncthreads();
    if (tid < TOPN) {
        u64 kw = ~removed_sh[tid >> 6];       // keep-word (invalid already removed)
        if ((kw >> (tid & 63)) & 1ull) {
            int rank = (int)wpref[tid >> 6] + (int)__popcll(kw & ((1ull << (tid & 63)) - 1ull));
            if (rank < MAXOBJ) {
                size_t o = (size_t)b * TOPN + tid;
                out_s[b * MAXOBJ + rank] = tscore[o];
                out_c[b * MAXOBJ + rank] = tcls[o];
                ((float4*)out_b)[b * MAXOBJ + rank] = tbox[o];
            }
        }
    }
}

// -------------------------------------------------------------------------
// Workspace layout (bytes), total 4,226,176.  Nothing needs pre-zeroing:
//   keys    u32 [16][21824]     @ 0
//   clsidx  i32 [16][21824]     @ 1,396,736
//   tscore  f32 [16][1000]      @ 2,793,472
//   tcls    f32 [16][1000]      @ 2,857,472
//   tbox    f4  [16][1000]      @ 2,921,472
//   sup     u64 [16][1000][16]  @ 3,177,472  (iou output; clobbers candbuf)
//   candbuf u64 [16][8192]      @ 3,177,472  (dead after rank)
//   params  u32 [16][2]         @ 4,226,048  {M, target}
// -------------------------------------------------------------------------
extern "C" void kernel_launch(void* const* d_in, const int* in_sizes, int n_in,
                              void* d_out, int out_size, void* d_ws, size_t ws_size,
                              hipStream_t stream) {
    (void)in_sizes; (void)n_in; (void)out_size; (void)ws_size;
    const float* cls[5]; const float* reg[5]; const float* ctr[5];
    for (int l = 0; l < 5; ++l) {
        cls[l] = (const float*)d_in[4 * l + 0];
        reg[l] = (const float*)d_in[4 * l + 1];
        ctr[l] = (const float*)d_in[4 * l + 2];
    }
    char* w = (char*)d_ws;
    u32*    keys   = (u32*)(w + 0);
    int*    clsidx = (int*)(w + 1396736);
    float*  tscore = (float*)(w + 2793472);
    float*  tcls   = (float*)(w + 2857472);
    float4* tbox   = (float4*)(w + 2921472);
    u64*    sup    = (u64*)(w + 3177472);
    u64*    candbuf= (u64*)(w + 3177472);
    u32*    params = (u32*)(w + 4226048);

    decode_kernel<<<dim3((NTOT + 127) / 128, NBATCH), 256, 0, stream>>>(
        cls[0], cls[1], cls[2], cls[3], cls[4],
        ctr[0], ctr[1], ctr[2], ctr[3], ctr[4],
        keys, clsidx);
    pivot_gather_kernel<<<NBATCH, 1024, 0, stream>>>(keys, candbuf, params,
                                                     tscore, tcls, tbox);
    rank_kernel<<<dim3(8, NBATCH), 256, 0, stream>>>(candbuf, params, clsidx,
                                                     reg[0], reg[1], reg[2], reg[3], reg[4],
                                                     tscore, tcls, tbox);
    iou_kernel<<<dim3(TOPN / 4, NBATCH), 256, 0, stream>>>(tbox, sup);
    finalize_kernel<<<NBATCH, 1024, 0, stream>>>(tscore, tcls, tbox, sup, (float*)d_out);
}